// Round 1
// baseline (119.724 us; speedup 1.0000x reference)
//
#include <hip/hip_runtime.h>
#include <hip/hip_bf16.h>

typedef __hip_bfloat16 bf16;
typedef short bf16x8 __attribute__((ext_vector_type(8)));
typedef float f32x4 __attribute__((ext_vector_type(4)));

#define S_LEN 4096
#define NBATCH 2
#define EDIM 1024
#define DDIM 64
#define MROWS (NBATCH * S_LEN)   // 8192

#define GLOBAL_AS __attribute__((address_space(1)))
#define LDS_AS __attribute__((address_space(3)))

union frag_u { bf16x8 v; bf16 e[8]; };

// async 16B global -> LDS (dest wave-uniform; HW adds lane*16; src per-lane)
__device__ __forceinline__ void async_ld16(const void* gp, void* lp) {
  __builtin_amdgcn_global_load_lds((const GLOBAL_AS void*)gp,
                                   (LDS_AS void*)lp, 16, 0, 0);
}

// f32x8 -> split bf16 hi/lo fragments (x ~= hi + lo, rel err ~2^-17)
__device__ __forceinline__ void cvt_split(const float4& a, const float4& b,
                                          bf16x8& hi, bf16x8& lo) {
  float v[8] = {a.x, a.y, a.z, a.w, b.x, b.y, b.z, b.w};
  frag_u h, l;
#pragma unroll
  for (int e = 0; e < 8; e++) {
    bf16 hh = __float2bfloat16(v[e]);
    h.e[e] = hh;
    l.e[e] = __float2bfloat16(v[e] - __bfloat162float(hh));
  }
  hi = h.v;
  lo = l.v;
}

// ---------------------------------------------------------------------------
// Pack weights (f32, k-major [1024][64]) -> split-bf16 in ROUND-MAJOR
// STAGING ORDER: Wt2[j=0..31][unit u=0..767][8 bf16], where round j covers
// k in [j*32, j*32+32). Unit for (n, kk): n2 = n>>1, pp = (n&1)*4 + (kk>>3),
// sp = pp ^ (n2 & 7)  (XOR swizzle -> 2-way-free LDS reads),
// u = n2*8 + sp, elem = kk&7.  A round block = 12288 B, byte-identical to
// its LDS image, so gemm B staging is a pure contiguous memcpy.
// Grid 48 = 3 mats x 16 k-blocks; LDS 64x65 transpose keeps reads coalesced.
// Block 0 zeroes Vsum.
// ---------------------------------------------------------------------------
__global__ __launch_bounds__(256) void pack_w_kernel(
    const float* __restrict__ Wq, const float* __restrict__ Wk,
    const float* __restrict__ Wv, bf16* __restrict__ Wt2_hi,
    bf16* __restrict__ Wt2_lo, float* __restrict__ Vsum) {
  __shared__ float tile[64 * 65];
  const int mat = blockIdx.x >> 4;
  const int kb = blockIdx.x & 15;             // 64-k block -> rounds 2kb,2kb+1
  const int t = threadIdx.x;
  if (blockIdx.x == 0 && t < NBATCH * DDIM) Vsum[t] = 0.f;
  const float* W = (mat == 0) ? Wq : ((mat == 1) ? Wk : Wv);

#pragma unroll
  for (int i = 0; i < 4; i++) {
    int F = (i * 256 + t) * 4;                // flat f32 idx in [0,4096)
    int k = F >> 6;
    int n4 = F & 63;
    float4 v = *(const float4*)(const void*)(W + (size_t)(kb * 64 + k) * 64 + n4);
    tile[(n4 + 0) * 65 + k] = v.x;
    tile[(n4 + 1) * 65 + k] = v.y;
    tile[(n4 + 2) * 65 + k] = v.z;
    tile[(n4 + 3) * 65 + k] = v.w;
  }
  __syncthreads();

  // 512 units (hi+lo written together): nl, j_half, pp_k
#pragma unroll
  for (int it = 0; it < 2; it++) {
    int uidx = it * 256 + t;
    int nl = uidx >> 3;
    int j_half = (uidx >> 2) & 1;
    int pp_k = uidx & 3;
    int ng = mat * 64 + nl;                   // global n in [0,192)
    int n2 = ng >> 1;
    int sp = ((ng & 1) * 4 + pp_k) ^ (n2 & 7);
    int unit = n2 * 8 + sp;
    int j = kb * 2 + j_half;
    frag_u h, l;
#pragma unroll
    for (int e = 0; e < 8; e++) {
      float v = tile[nl * 65 + j_half * 32 + pp_k * 8 + e];
      bf16 hh = __float2bfloat16(v);
      h.e[e] = hh;
      l.e[e] = __float2bfloat16(v - __bfloat162float(hh));
    }
    size_t ob = (size_t)j * 6144 + unit * 8;
    *(bf16x8*)(void*)(Wt2_hi + ob) = h.v;
    *(bf16x8*)(void*)(Wt2_lo + ob) = l.v;
  }
}

// ---------------------------------------------------------------------------
// Fused QKV GEMM v6 — v5 + deep pipeline with COUNTED vmcnt (no barrier
// drain).  v5 was latency-bound: __syncthreads() drained vmcnt to 0 every
// round => round time ~= full global->LDS latency (MfmaUtil 7.6%).
// Now: 4 x 28 KB LDS ring, prefetch depth 3, per-round sequence
//   s_waitcnt vmcnt(2*nch)   (own round-j loads landed; j+1,j+2 in flight)
//   s_barrier                (=> ALL waves' round-j loads landed)
//   stage round j+3 into buf (j+3)%4   (holds round j-1: everyone passed
//                                       this barrier after computing j-1)
//   compute round j
// Loads stay in flight across barriers with ~3 rounds of slack (> HBM
// latency ~900 cyc).  M=8192, K=1024, N=192. Grid 256 x 512 (8 waves,
// 1 block/CU, LDS 112 KB).  Staging layout unchanged from v5:
//   chunks 0-3   A: 8 rows x 128B segments, lane=(row<<3)|p, src part
//                p ^ (row&7)  -> LDS pos (row*8 + (part^(row&7)))*16B
//   chunks 4-15  Bh: byte-copy of Wt2_hi round block (pre-swizzled)
//   chunks 16-27 Bl: byte-copy of Wt2_lo round block
// Fragment reads (both 2-way bank conflict = free):
//   A: lane(l16,quad) float4 @ (l16*8 + ((quad*2+s)^(l16&7)))*16, s=0,1
//   B: lane(l16,quad) b128  @ ((nt*8+(l16>>1))*8 + (((l16&1)*4+quad)^((l16>>1)&7)))*16
// Wave (mt,nh): mt = 16-row half, nh -> n-tiles nh*3..nh*3+2; 9 MFMA/round.
// Epilogue: bias + store qkv; V-column sums -> Vsum atomics.
// MFMA f32_16x16x32_bf16 split-bf16 (xh*wh + xh*wl + xl*wh):
//   A[m][k]: m=lane&15, k=(lane>>4)*8+e | B[k][n]: n=lane&15, k=(lane>>4)*8+e
//   D[m][n]: m=(lane>>4)*4+r, n=lane&15
// ---------------------------------------------------------------------------
#define WAITV8 asm volatile("s_waitcnt vmcnt(8)" ::: "memory")
#define WAITV6 asm volatile("s_waitcnt vmcnt(6)" ::: "memory")

__global__ __launch_bounds__(512, 2) void qkv_gemm_kernel(
    const float* __restrict__ x, const bf16* __restrict__ Wt2_hi,
    const bf16* __restrict__ Wt2_lo, const float* __restrict__ bq,
    const float* __restrict__ bk, const float* __restrict__ bv,
    float* __restrict__ qkv, float* __restrict__ Vsum) {
  __shared__ __align__(16) char lds[114688];  // 4 x 28 KB ring
  const int tid = threadIdx.x;
  const int lane = tid & 63;
  const int wave = tid >> 6;
  const int quad = lane >> 4;
  const int l16 = lane & 15;
  const int mt = wave >> 2;
  const int nh = wave & 3;
  const int rowBase = blockIdx.x * 32;

  // staging chunk assignment: wave w owns chunks {w, w+8, w+16, w+24(<28)}
  const char* gsrc[4];
  int gstride[4], ldoff[4];
  const int nch = (wave < 4) ? 4 : 3;
#pragma unroll
  for (int s = 0; s < 4; s++) {
    int c = wave + s * 8;
    ldoff[s] = c * 1024;
    if (c < 4) {                              // A: rows c*8..c*8+7
      int rin = lane >> 3;                    // row within chunk (=(row&7))
      int part = (lane & 7) ^ rin;            // source 16B part (swizzled)
      gsrc[s] = (const char*)(x + (size_t)(rowBase + c * 8 + rin) * EDIM +
                              part * 4);
      gstride[s] = 128;                       // 32 f32 per round
    } else if (c < 16) {
      gsrc[s] = (const char*)Wt2_hi + (c - 4) * 1024 + lane * 16;
      gstride[s] = 12288;                     // one round block
    } else {
      gsrc[s] = (const char*)Wt2_lo + (c - 16) * 1024 + lane * 16;
      gstride[s] = 12288;
    }
  }

  f32x4 acc[3];
#pragma unroll
  for (int t = 0; t < 3; t++) acc[t] = (f32x4){0.f, 0.f, 0.f, 0.f};

  // prologue: stage rounds 0..2 into bufs 0..2 (depth-3 prefetch)
#pragma unroll
  for (int r = 0; r < 3; r++)
#pragma unroll
    for (int s = 0; s < 4; s++)
      if (s < nch)
        async_ld16(gsrc[s] + (size_t)r * gstride[s],
                   lds + r * 28672 + ldoff[s]);

  const int arow = mt * 16 + l16;             // row&7 == l16&7 (mt*16%8==0)
  const int asp0 = (quad * 2) ^ (l16 & 7);
  for (int j = 0; j < 32; j++) {
    // own round-j loads landed (j+1, j+2 may still be in flight)
    if (nch == 4) WAITV8; else WAITV6;
    __builtin_amdgcn_s_barrier();             // all waves' round-j loads in
    asm volatile("" ::: "memory");            // no LDS reads hoist above here

    if (j + 3 < 32) {                         // stage j+3 (buf held j-1)
      char* nb = lds + ((j + 3) & 3) * 28672;
#pragma unroll
      for (int s = 0; s < 4; s++)
        if (s < nch)
          async_ld16(gsrc[s] + (size_t)(j + 3) * gstride[s], nb + ldoff[s]);
    }

    const char* Ab = lds + (j & 3) * 28672;
    const bf16* Bhb = (const bf16*)(Ab + 4096);
    const bf16* Blb = (const bf16*)(Ab + 16384);
    float4 a0 = *(const float4*)(const void*)(Ab + (arow * 8 + asp0) * 16);
    float4 a1 = *(const float4*)(const void*)(Ab + (arow * 8 + (asp0 ^ 1)) * 16);
    bf16x8 ah, al;
    cvt_split(a0, a1, ah, al);
#pragma unroll
    for (int t = 0; t < 3; t++) {
      int nt = nh * 3 + t;
      int n2 = nt * 8 + (l16 >> 1);
      int sp = (((l16 & 1) * 4) + quad) ^ ((l16 >> 1) & 7);
      int uoff = (n2 * 8 + sp) * 8;           // bf16 offset
      bf16x8 bh = *(const bf16x8*)(const void*)(Bhb + uoff);
      bf16x8 bl = *(const bf16x8*)(const void*)(Blb + uoff);
      acc[t] = __builtin_amdgcn_mfma_f32_16x16x32_bf16(ah, bh, acc[t], 0, 0, 0);
      acc[t] = __builtin_amdgcn_mfma_f32_16x16x32_bf16(ah, bl, acc[t], 0, 0, 0);
      acc[t] = __builtin_amdgcn_mfma_f32_16x16x32_bf16(al, bh, acc[t], 0, 0, 0);
    }
    // no __syncthreads: next iteration's waitcnt+barrier provides the sync;
    // buffer overwritten only after every wave passed a barrier post-compute
  }

  // epilogue: bias + store + V column sums
  const int bb = rowBase >> 12;
#pragma unroll
  for (int t = 0; t < 3; t++) {
    int nt = nh * 3 + t;
    int n = nt * 16 + l16;
    int mat = n >> 6;
    int col = n & 63;
    float bias = (mat == 0) ? bq[col] : ((mat == 1) ? bk[col] : bv[col]);
    float* dst = qkv + (size_t)mat * MROWS * DDIM +
                 (size_t)(rowBase + mt * 16 + quad * 4) * DDIM + col;
    float vs = 0.f;
#pragma unroll
    for (int r = 0; r < 4; r++) {
      float val = acc[t][r] + bias;
      dst[r * DDIM] = val;
      vs += val;
    }
    if (nt >= 8) {                            // V tiles -> Vsum
      vs += __shfl_xor(vs, 16, 64);
      vs += __shfl_xor(vs, 32, 64);
      if (quad == 0) atomicAdd(&Vsum[bb * DDIM + (n - 128)], vs);
    }
  }
}

// ---------------------------------------------------------------------------
// Attention: 2 queries per wave, 32 lanes each, lane owns a float2 dim-pair.
// Full-row softmax collapses to: 5 window exps + (S - nvalid) background
// exp(0-m) terms; background numerator = Vsum - sum(window V).
// ---------------------------------------------------------------------------
__global__ __launch_bounds__(256) void attn_kernel(
    const float* __restrict__ qkv, const float* __restrict__ Vsum,
    float* __restrict__ out) {
  const float* Qf = qkv;
  const float* Kf = qkv + (size_t)MROWS * DDIM;
  const float* Vf = qkv + (size_t)2 * MROWS * DDIM;
  int l = threadIdx.x & 31;
  int qidx = blockIdx.x * 8 + (threadIdx.x >> 5);
  int b = qidx >> 12;
  int i = qidx & 4095;

  float2 q = *(const float2*)(const void*)(Qf + (size_t)qidx * DDIM + 2 * l);
  float sc[5];
  float2 vv[5];
  bool val[5];
#pragma unroll
  for (int w = 0; w < 5; w++) {
    int j = i + 2 * w - 4;                    // DIL*(w - WIN/2), DIL=2
    val[w] = (j >= 0) && (j < S_LEN);
    int jj = val[w] ? j : i;
    size_t off = (size_t)(b * S_LEN + jj) * DDIM + 2 * l;
    float2 kk = *(const float2*)(const void*)(Kf + off);
    vv[w] = *(const float2*)(const void*)(Vf + off);
    float p = q.x * kk.x + q.y * kk.y;
#pragma unroll
    for (int d = 1; d < 32; d <<= 1) p += __shfl_xor(p, d, 64);
    sc[w] = p;
  }

  float mx = 0.f;                             // background score 0 in the max
#pragma unroll
  for (int w = 0; w < 5; w++)
    if (val[w]) mx = fmaxf(mx, sc[w]);

  float denom = 0.f;
  float2 accv = {0.f, 0.f}, vsel = {0.f, 0.f};
  int nval = 0;
#pragma unroll
  for (int w = 0; w < 5; w++)
    if (val[w]) {
      float pexp = __expf(sc[w] - mx);
      denom += pexp;
      accv.x += pexp * vv[w].x;
      accv.y += pexp * vv[w].y;
      vsel.x += vv[w].x;
      vsel.y += vv[w].y;
      nval++;
    }
  float pbg = __expf(-mx);
  denom += pbg * (float)(S_LEN - nval);
  float2 vsm = *(const float2*)(const void*)(Vsum + b * DDIM + 2 * l);
  accv.x += pbg * (vsm.x - vsel.x);
  accv.y += pbg * (vsm.y - vsel.y);

  float2 o = {accv.x / denom, accv.y / denom};
  *(float2*)(void*)(out + (size_t)qidx * DDIM + 2 * l) = o;
}

// ---------------------------------------------------------------------------
extern "C" void kernel_launch(void* const* d_in, const int* in_sizes, int n_in,
                              void* d_out, int out_size, void* d_ws,
                              size_t ws_size, hipStream_t stream) {
  const float* x = (const float*)d_in[0];
  const float* Wq = (const float*)d_in[1];
  const float* bq = (const float*)d_in[2];
  const float* Wk = (const float*)d_in[3];
  const float* bk = (const float*)d_in[4];
  const float* Wv = (const float*)d_in[5];
  const float* bv = (const float*)d_in[6];
  float* out = (float*)d_out;

  char* ws = (char*)d_ws;
  bf16* Wt2_hi = (bf16*)ws;                   // 32*6144*2 = 393216 B
  bf16* Wt2_lo = (bf16*)(ws + 393216);        // 393216 B
  float* qkv = (float*)(ws + 786432);         // 3*8192*64*4 = 6291456 B
  float* Vsum = (float*)(ws + 786432 + 6291456);  // 512 B
  // total workspace ~7.1 MB

  hipLaunchKernelGGL(pack_w_kernel, dim3(48), dim3(256), 0, stream, Wq, Wk, Wv,
                     Wt2_hi, Wt2_lo, Vsum);
  hipLaunchKernelGGL(qkv_gemm_kernel, dim3(256), dim3(512), 0, stream, x,
                     Wt2_hi, Wt2_lo, bq, bk, bv, qkv, Vsum);
  hipLaunchKernelGGL(attn_kernel, dim3(1024), dim3(256), 0, stream, qkv, Vsum,
                     out);
}

// Round 2
// 109.501 us; speedup vs baseline: 1.0934x; 1.0934x over previous
//
#include <hip/hip_runtime.h>
#include <hip/hip_bf16.h>

typedef __hip_bfloat16 bf16;
typedef short bf16x8 __attribute__((ext_vector_type(8)));
typedef float f32x4 __attribute__((ext_vector_type(4)));

#define S_LEN 4096
#define NBATCH 2
#define EDIM 1024
#define DDIM 64
#define MROWS (NBATCH * S_LEN)   // 8192

#define GLOBAL_AS __attribute__((address_space(1)))
#define LDS_AS __attribute__((address_space(3)))

union frag_u { bf16x8 v; bf16 e[8]; };

// async 16B global -> LDS (dest wave-uniform; HW adds lane*16; src per-lane)
__device__ __forceinline__ void async_ld16(const void* gp, void* lp) {
  __builtin_amdgcn_global_load_lds((const GLOBAL_AS void*)gp,
                                   (LDS_AS void*)lp, 16, 0, 0);
}

// f32x8 -> split bf16 hi/lo fragments (x ~= hi + lo, rel err ~2^-17)
__device__ __forceinline__ void cvt_split(const float4& a, const float4& b,
                                          bf16x8& hi, bf16x8& lo) {
  float v[8] = {a.x, a.y, a.z, a.w, b.x, b.y, b.z, b.w};
  frag_u h, l;
#pragma unroll
  for (int e = 0; e < 8; e++) {
    bf16 hh = __float2bfloat16(v[e]);
    h.e[e] = hh;
    l.e[e] = __float2bfloat16(v[e] - __bfloat162float(hh));
  }
  hi = h.v;
  lo = l.v;
}

// ---------------------------------------------------------------------------
// Pack weights (f32, k-major [1024][64]) -> split-bf16 in ROUND-MAJOR
// order: Wt2[j=0..31][unit u=0..767][8 bf16], round j covers k in
// [j*32, j*32+32). Unit for (n, kk): n2 = n>>1, pp = (n&1)*4 + (kk>>3),
// sp = pp ^ (n2 & 7), u = n2*8 + sp, elem = kk&7. A round block = 12288 B.
// The gemm now reads lane units DIRECTLY from global (each (nt, round) is a
// contiguous, fully-consumed 1 KB segment -> perfect coalescing, L2-hot).
// Grid 48 = 3 mats x 16 k-blocks. Block 0 zeroes Vsum.
// ---------------------------------------------------------------------------
__global__ __launch_bounds__(256) void pack_w_kernel(
    const float* __restrict__ Wq, const float* __restrict__ Wk,
    const float* __restrict__ Wv, bf16* __restrict__ Wt2_hi,
    bf16* __restrict__ Wt2_lo, float* __restrict__ Vsum) {
  __shared__ float tile[64 * 65];
  const int mat = blockIdx.x >> 4;
  const int kb = blockIdx.x & 15;             // 64-k block -> rounds 2kb,2kb+1
  const int t = threadIdx.x;
  if (blockIdx.x == 0 && t < NBATCH * DDIM) Vsum[t] = 0.f;
  const float* W = (mat == 0) ? Wq : ((mat == 1) ? Wk : Wv);

#pragma unroll
  for (int i = 0; i < 4; i++) {
    int F = (i * 256 + t) * 4;                // flat f32 idx in [0,4096)
    int k = F >> 6;
    int n4 = F & 63;
    float4 v = *(const float4*)(const void*)(W + (size_t)(kb * 64 + k) * 64 + n4);
    tile[(n4 + 0) * 65 + k] = v.x;
    tile[(n4 + 1) * 65 + k] = v.y;
    tile[(n4 + 2) * 65 + k] = v.z;
    tile[(n4 + 3) * 65 + k] = v.w;
  }
  __syncthreads();

  // 512 units (hi+lo written together): nl, j_half, pp_k
#pragma unroll
  for (int it = 0; it < 2; it++) {
    int uidx = it * 256 + t;
    int nl = uidx >> 3;
    int j_half = (uidx >> 2) & 1;
    int pp_k = uidx & 3;
    int ng = mat * 64 + nl;                   // global n in [0,192)
    int n2 = ng >> 1;
    int sp = ((ng & 1) * 4 + pp_k) ^ (n2 & 7);
    int unit = n2 * 8 + sp;
    int j = kb * 2 + j_half;
    frag_u h, l;
#pragma unroll
    for (int e = 0; e < 8; e++) {
      float v = tile[nl * 65 + j_half * 32 + pp_k * 8 + e];
      bf16 hh = __float2bfloat16(v);
      h.e[e] = hh;
      l.e[e] = __float2bfloat16(v - __bfloat162float(hh));
    }
    size_t ob = (size_t)j * 6144 + unit * 8;
    *(bf16x8*)(void*)(Wt2_hi + ob) = h.v;
    *(bf16x8*)(void*)(Wt2_lo + ob) = l.v;
  }
}

// ---------------------------------------------------------------------------
// Fused QKV GEMM v7 — B direct-to-register (the v5/v6 zero-delta post-mortem:
// 28 KB/round through the LDS-DMA path is a ~16-21 B/cy/CU THROUGHPUT wall,
// which is why depth-3 pipelining changed nothing). Now only A (2 KB/round)
// uses global_load_lds; B fragments are plain global_load_dwordx4 into a
// register double-buffer (each (nt, round) unit is 16 B/lane inside a
// contiguous 1 KB segment -> perfect coalescing; Wt2 is L2-resident).
//
// Block = 16 rows x N=192, 4 waves (wave = nh, 3 n-tiles each), grid 512
// -> ~2 blocks/CU overlap. LDS = ring of 4 A-groups (group g = BK=64,
// rounds 2g/2g+1, 4 KB): EVERY wave issues exactly 1 DMA per group
// (wave w: rows (w&1)*8..+7, k-half w>>1) -> uniform code, exact waitcnt.
// Even rounds: s_waitcnt vmcnt(7) (own group landed; outstanding =
// [g+1 DMA, 6 B-loads]) + s_barrier certifies cross-wave A. Odd rounds:
// no barrier (same group, other k-half). The compiler's in-order vmcnt
// waits for B consumption retire A-DMAs 2+ rounds ahead of need.
// A LDS unit(r,p) = r*8 + (p^(r&7)) -- read formula unchanged from v5.
// MFMA f32_16x16x32_bf16 split-bf16 (xh*wh + xh*wl + xl*wh):
//   A[m][k]: m=lane&15, k=(lane>>4)*8+e | B[k][n]: n=lane&15, k=(lane>>4)*8+e
//   D[m][n]: m=(lane>>4)*4+r, n=lane&15
// ---------------------------------------------------------------------------
__global__ __launch_bounds__(256, 2) void qkv_gemm_kernel(
    const float* __restrict__ x, const bf16* __restrict__ Wt2_hi,
    const bf16* __restrict__ Wt2_lo, const float* __restrict__ bq,
    const float* __restrict__ bk, const float* __restrict__ bv,
    float* __restrict__ qkv, float* __restrict__ Vsum) {
  __shared__ __align__(16) char lds[16384];   // 4-slot ring of 4 KB A-groups
  const int tid = threadIdx.x;
  const int lane = tid & 63;
  const int wave = tid >> 6;                  // = nh
  const int quad = lane >> 4;
  const int l16 = lane & 15;
  const int rowBase = blockIdx.x * 16;

  // A staging: wave w stages rows (w&1)*8..+7, k-half (w>>1) of each group
  const int rin = lane >> 3;
  const int part = (lane & 7) ^ rin;          // XOR swizzle (matches read)
  const char* aSrc = (const char*)x +
      (size_t)(rowBase + (wave & 1) * 8 + rin) * (EDIM * 4) +
      (wave >> 1) * 128 + part * 16;
  char* aDstU = lds + (wave >> 1) * 2048 + (wave & 1) * 1024;  // + slot*4096

  // B lane base (pre-swizzled pack layout): unit = nt*512 + loff bf16
  const int sp = ((l16 & 1) * 4 + quad) ^ ((l16 >> 1) & 7);
  const int loff = ((l16 >> 1) * 8 + sp) * 8;
  const bf16* bhp = Wt2_hi + wave * 1536 + loff;
  const bf16* blp = Wt2_lo + wave * 1536 + loff;

  f32x4 acc[3];
#pragma unroll
  for (int t = 0; t < 3; t++) acc[t] = (f32x4){0.f, 0.f, 0.f, 0.f};

  // prologue: A groups 0,1 (rounds 0..3); B round 0 -> (h*,l*)
  async_ld16(aSrc, aDstU);
  async_ld16(aSrc + 256, aDstU + 4096);
  bf16x8 h0, h1, h2, l0, l1, l2, H0, H1, H2, L0, L1, L2;
  h0 = *(const bf16x8*)(const void*)(bhp);
  h1 = *(const bf16x8*)(const void*)(bhp + 512);
  h2 = *(const bf16x8*)(const void*)(bhp + 1024);
  l0 = *(const bf16x8*)(const void*)(blp);
  l1 = *(const bf16x8*)(const void*)(blp + 512);
  l2 = *(const bf16x8*)(const void*)(blp + 1024);

  const int asp0 = (quad * 2) ^ (l16 & 7);
  const int aoff0 = (l16 * 8 + asp0) * 16;
  const int aoff1 = (l16 * 8 + (asp0 ^ 1)) * 16;

#define COMPUTE(JJ, BH0, BH1, BH2, BL0, BL1, BL2)                              \
  {                                                                            \
    const char* Ab = lds + (((JJ) >> 1) & 3) * 4096 + ((JJ) & 1) * 2048;       \
    float4 a0 = *(const float4*)(const void*)(Ab + aoff0);                     \
    float4 a1 = *(const float4*)(const void*)(Ab + aoff1);                     \
    bf16x8 ah, al;                                                             \
    cvt_split(a0, a1, ah, al);                                                 \
    acc[0] = __builtin_amdgcn_mfma_f32_16x16x32_bf16(ah, BH0, acc[0], 0, 0, 0);\
    acc[0] = __builtin_amdgcn_mfma_f32_16x16x32_bf16(ah, BL0, acc[0], 0, 0, 0);\
    acc[0] = __builtin_amdgcn_mfma_f32_16x16x32_bf16(al, BH0, acc[0], 0, 0, 0);\
    acc[1] = __builtin_amdgcn_mfma_f32_16x16x32_bf16(ah, BH1, acc[1], 0, 0, 0);\
    acc[1] = __builtin_amdgcn_mfma_f32_16x16x32_bf16(ah, BL1, acc[1], 0, 0, 0);\
    acc[1] = __builtin_amdgcn_mfma_f32_16x16x32_bf16(al, BH1, acc[1], 0, 0, 0);\
    acc[2] = __builtin_amdgcn_mfma_f32_16x16x32_bf16(ah, BH2, acc[2], 0, 0, 0);\
    acc[2] = __builtin_amdgcn_mfma_f32_16x16x32_bf16(ah, BL2, acc[2], 0, 0, 0);\
    acc[2] = __builtin_amdgcn_mfma_f32_16x16x32_bf16(al, BH2, acc[2], 0, 0, 0);\
  }

  for (int j = 0; j < 32; j += 2) {
    // ---- even round j ----
    asm volatile("s_waitcnt vmcnt(7)" ::: "memory");  // group j/2 landed
    __builtin_amdgcn_s_barrier();                     // all waves' chunks in
    asm volatile("" ::: "memory");                    // no LDS-read hoisting
    {  // B prefetch round j+1 -> (H*,L*)
      const bf16* bh = bhp + (size_t)(j + 1) * 6144;
      const bf16* bl = blp + (size_t)(j + 1) * 6144;
      H0 = *(const bf16x8*)(const void*)(bh);
      H1 = *(const bf16x8*)(const void*)(bh + 512);
      H2 = *(const bf16x8*)(const void*)(bh + 1024);
      L0 = *(const bf16x8*)(const void*)(bl);
      L1 = *(const bf16x8*)(const void*)(bl + 512);
      L2 = *(const bf16x8*)(const void*)(bl + 1024);
    }
    asm volatile("" ::: "memory");  // pin DMA AFTER B loads (issue order ->
                                    // B-use waits don't drag fresh DMA along)
    if (j + 4 < 32)                 // stage group j/2+2 (rounds j+4, j+5)
      async_ld16(aSrc + (size_t)(j / 2 + 2) * 256,
                 aDstU + ((j / 2 + 2) & 3) * 4096);
    COMPUTE(j, h0, h1, h2, l0, l1, l2);
    // ---- odd round j+1 ---- (same A group, other k-half; no sync needed)
    {  // B prefetch round j+2 -> (h*,l*); clamp at tail (redundant reload)
      int jn = (j + 2 < 32) ? (j + 2) : 31;
      const bf16* bh = bhp + (size_t)jn * 6144;
      const bf16* bl = blp + (size_t)jn * 6144;
      h0 = *(const bf16x8*)(const void*)(bh);
      h1 = *(const bf16x8*)(const void*)(bh + 512);
      h2 = *(const bf16x8*)(const void*)(bh + 1024);
      l0 = *(const bf16x8*)(const void*)(bl);
      l1 = *(const bf16x8*)(const void*)(bl + 512);
      l2 = *(const bf16x8*)(const void*)(bl + 1024);
    }
    COMPUTE(j + 1, H0, H1, H2, L0, L1, L2);
  }
#undef COMPUTE

  // epilogue: bias + store + V column sums
  const int bb = rowBase >> 12;
#pragma unroll
  for (int t = 0; t < 3; t++) {
    int nt = wave * 3 + t;
    int n = nt * 16 + l16;
    int mat = n >> 6;
    int col = n & 63;
    float bias = (mat == 0) ? bq[col] : ((mat == 1) ? bk[col] : bv[col]);
    float* dst = qkv + (size_t)mat * MROWS * DDIM +
                 (size_t)(rowBase + quad * 4) * DDIM + col;
    float vs = 0.f;
#pragma unroll
    for (int r = 0; r < 4; r++) {
      float val = acc[t][r] + bias;
      dst[r * DDIM] = val;
      vs += val;
    }
    if (nt >= 8) {                            // V tiles -> Vsum
      vs += __shfl_xor(vs, 16, 64);
      vs += __shfl_xor(vs, 32, 64);
      if (quad == 0) atomicAdd(&Vsum[bb * DDIM + (n - 128)], vs);
    }
  }
}

// ---------------------------------------------------------------------------
// Attention: 2 queries per wave, 32 lanes each, lane owns a float2 dim-pair.
// Full-row softmax collapses to: 5 window exps + (S - nvalid) background
// exp(0-m) terms; background numerator = Vsum - sum(window V).
// ---------------------------------------------------------------------------
__global__ __launch_bounds__(256) void attn_kernel(
    const float* __restrict__ qkv, const float* __restrict__ Vsum,
    float* __restrict__ out) {
  const float* Qf = qkv;
  const float* Kf = qkv + (size_t)MROWS * DDIM;
  const float* Vf = qkv + (size_t)2 * MROWS * DDIM;
  int l = threadIdx.x & 31;
  int qidx = blockIdx.x * 8 + (threadIdx.x >> 5);
  int b = qidx >> 12;
  int i = qidx & 4095;

  float2 q = *(const float2*)(const void*)(Qf + (size_t)qidx * DDIM + 2 * l);
  float sc[5];
  float2 vv[5];
  bool val[5];
#pragma unroll
  for (int w = 0; w < 5; w++) {
    int j = i + 2 * w - 4;                    // DIL*(w - WIN/2), DIL=2
    val[w] = (j >= 0) && (j < S_LEN);
    int jj = val[w] ? j : i;
    size_t off = (size_t)(b * S_LEN + jj) * DDIM + 2 * l;
    float2 kk = *(const float2*)(const void*)(Kf + off);
    vv[w] = *(const float2*)(const void*)(Vf + off);
    float p = q.x * kk.x + q.y * kk.y;
#pragma unroll
    for (int d = 1; d < 32; d <<= 1) p += __shfl_xor(p, d, 64);
    sc[w] = p;
  }

  float mx = 0.f;                             // background score 0 in the max
#pragma unroll
  for (int w = 0; w < 5; w++)
    if (val[w]) mx = fmaxf(mx, sc[w]);

  float denom = 0.f;
  float2 accv = {0.f, 0.f}, vsel = {0.f, 0.f};
  int nval = 0;
#pragma unroll
  for (int w = 0; w < 5; w++)
    if (val[w]) {
      float pexp = __expf(sc[w] - mx);
      denom += pexp;
      accv.x += pexp * vv[w].x;
      accv.y += pexp * vv[w].y;
      vsel.x += vv[w].x;
      vsel.y += vv[w].y;
      nval++;
    }
  float pbg = __expf(-mx);
  denom += pbg * (float)(S_LEN - nval);
  float2 vsm = *(const float2*)(const void*)(Vsum + b * DDIM + 2 * l);
  accv.x += pbg * (vsm.x - vsel.x);
  accv.y += pbg * (vsm.y - vsel.y);

  float2 o = {accv.x / denom, accv.y / denom};
  *(float2*)(void*)(out + (size_t)qidx * DDIM + 2 * l) = o;
}

// ---------------------------------------------------------------------------
extern "C" void kernel_launch(void* const* d_in, const int* in_sizes, int n_in,
                              void* d_out, int out_size, void* d_ws,
                              size_t ws_size, hipStream_t stream) {
  const float* x = (const float*)d_in[0];
  const float* Wq = (const float*)d_in[1];
  const float* bq = (const float*)d_in[2];
  const float* Wk = (const float*)d_in[3];
  const float* bk = (const float*)d_in[4];
  const float* Wv = (const float*)d_in[5];
  const float* bv = (const float*)d_in[6];
  float* out = (float*)d_out;

  char* ws = (char*)d_ws;
  bf16* Wt2_hi = (bf16*)ws;                   // 32*6144*2 = 393216 B
  bf16* Wt2_lo = (bf16*)(ws + 393216);        // 393216 B
  float* qkv = (float*)(ws + 786432);         // 3*8192*64*4 = 6291456 B
  float* Vsum = (float*)(ws + 786432 + 6291456);  // 512 B
  // total workspace ~7.1 MB

  hipLaunchKernelGGL(pack_w_kernel, dim3(48), dim3(256), 0, stream, Wq, Wk, Wv,
                     Wt2_hi, Wt2_lo, Vsum);
  hipLaunchKernelGGL(qkv_gemm_kernel, dim3(512), dim3(256), 0, stream, x,
                     Wt2_hi, Wt2_lo, bq, bk, bv, qkv, Vsum);
  hipLaunchKernelGGL(attn_kernel, dim3(1024), dim3(256), 0, stream, qkv, Vsum,
                     out);
}